// Round 12
// baseline (256.012 us; speedup 1.0000x reference)
//
#include <hip/hip_runtime.h>

// LocalCorrRatio on (1,1,90,90,90) fp32. 1000 patches (9x9x9), 32 Parzen bins,
// 4 configs: conf = dir (X/Y swap) x shift (0/4).  out = -(1/12000)*sum eta^2.
//
// R4: one wave per (conf,patch) = 4000 blocks. Voxel-per-lane (12/lane).
// Parzen weights by multiplicative recurrence: u=31y, w_{b+1}=w_b*r, r*=e^-2,
// refreshed every 8 bins (w=h*h with h=exp(-d^2/2) for underflow safety).
// -> ~2.7 exps/voxel instead of 32. Zero cross-lane routing in the sweep;
// per-bin partials go through an 8.4KB LDS transpose once.

constexpr int   NPATCH = 1000;
constexpr float EM2    = 0.13533528323661270f;   // e^-2

__global__ __launch_bounds__(64)
void cr_patch_kernel(const float* __restrict__ yt,
                     const float* __restrict__ yp,
                     float* __restrict__ partial,    // [4*NPATCH]
                     unsigned* __restrict__ cnt,     // memset 0 per call
                     float* __restrict__ out)
{
    __shared__ float2 lds[32][33];                  // [bin][lane<32], +1 pad

    const int bid  = blockIdx.x;
    const int conf = bid / NPATCH;                  // 0..3
    const int p    = bid - conf * NPATCH;
    const int shift = (conf >= 2) ? 4 : 0;
    const int ph = p / 100, pw = (p / 10) % 10, pd = p % 10;
    const float* __restrict__ X = (conf & 1) ? yp : yt;   // intensity
    const float* __restrict__ Y = (conf & 1) ? yt : yp;   // binned
    const int lane = threadIdx.x;

    // ---- Load: lane owns voxels j = lane + 64*v ----
    float xv[12], uv[12];                           // x, u = 31*y
    float sx = 0.f, sx2 = 0.f;

    auto vload = [&](int j, float& x_, float& u_) {
        int dh  = j / 81;
        int rem = j - dh * 81;
        int dw  = rem / 9;
        int dd  = rem - dw * 9;
        int H = ph * 9 + dh + shift; if (H >= 90) H -= 90;
        int W = pw * 9 + dw + shift; if (W >= 90) W -= 90;
        int D = pd * 9 + dd + shift; if (D >= 90) D -= 90;
        int idx = (H * 90 + W) * 90 + D;
        x_ = X[idx];
        u_ = 31.0f * Y[idx];
    };

    #pragma unroll
    for (int v = 0; v < 11; ++v) {
        vload(lane + (v << 6), xv[v], uv[v]);
        sx += xv[v]; sx2 = fmaf(xv[v], xv[v], sx2);
    }
    if (lane < 729 - 11 * 64) {                     // lanes 0..24: 12th voxel
        vload(lane + 704, xv[11], uv[11]);
        sx += xv[11]; sx2 = fmaf(xv[11], xv[11], sx2);
    } else {
        xv[11] = 0.f;                               // no effect on sums
        uv[11] = -310.f;                            // w=0, r=exp(-621)=0 (finite!)
    }

    #pragma unroll
    for (int m = 1; m < 64; m <<= 1) {
        sx  += __shfl_xor(sx,  m);
        sx2 += __shfl_xor(sx2, m);
    }
    const float mean = sx * (1.0f / 729.0f);

    // ---- Bin sweep: 4 windows x 8 bins, 2-mul recurrence per bin ----
    float w[12], r[12];
    #pragma unroll
    for (int win = 0; win < 4; ++win) {
        const float b0 = (float)(8 * win);
        #pragma unroll
        for (int v = 0; v < 12; ++v) {              // refresh (2 exps/voxel)
            float d = uv[v] - b0;
            float h = __expf(-0.5f * d * d);        // half-exp: safe to |d|=14.3
            w[v] = h * h;                           // = exp(-d^2)
            r[v] = __expf(fmaf(2.0f, d, -1.0f));    // = exp(2d-1), max exp(61) ok
        }
        #pragma unroll
        for (int j = 0; j < 8; ++j) {               // bin b = 8*win + j
            float s = 0.f, t = 0.f;
            #pragma unroll
            for (int v = 0; v < 12; ++v) {
                s += w[v];
                t = fmaf(w[v], xv[v], t);
                w[v] *= r[v];                       // -> weight for b+1
                r[v] *= EM2;
            }
            s += __shfl_xor(s, 32);                 // fold upper half-wave
            t += __shfl_xor(t, 32);
            if (lane < 32) lds[8 * win + j][lane] = make_float2(s, t);
        }
    }
    __syncthreads();

    // ---- Transpose-reduce: bin-per-lane over 32 columns ----
    const int b    = lane & 31;
    const int half = lane >> 5;
    float Sw = 0.f, Swx = 0.f;
    #pragma unroll
    for (int l = 0; l < 16; ++l) {
        float2 q = lds[b][half * 16 + l];
        Sw += q.x; Swx += q.y;
    }
    Sw  += __shfl_xor(Sw,  32);
    Swx += __shfl_xor(Swx, 32);

    float mi = Swx / (Sw + 1e-5f);                  // weights_norm denom eps
    float du = mi - mean;
    float tn = Sw * du * du, td = Sw;
    #pragma unroll
    for (int m = 1; m < 32; m <<= 1) {              // reduce 32 bins
        tn += __shfl_xor(tn, m);
        td += __shfl_xor(td, m);
    }

    if (lane == 0) {
        float tv = (sx2 - sx * sx * (1.0f / 729.0f)) * (1.0f / 728.0f);  // ddof=1
        __hip_atomic_store(&partial[bid], (tn / td) / (tv + 1e-5f),
                           __ATOMIC_RELAXED, __HIP_MEMORY_SCOPE_AGENT);
    }

    // ---- Last-block final reduction ----
    __threadfence();
    unsigned old = 0;
    if (lane == 0)
        old = __hip_atomic_fetch_add(cnt, 1u, __ATOMIC_ACQ_REL, __HIP_MEMORY_SCOPE_AGENT);
    old = __shfl(old, 0, 64);
    if (old == 4u * NPATCH - 1u) {
        __threadfence();
        float s = 0.f;
        for (int i = lane; i < 4 * NPATCH; i += 64)
            s += __hip_atomic_load(&partial[i], __ATOMIC_RELAXED, __HIP_MEMORY_SCOPE_AGENT);
        #pragma unroll
        for (int m = 1; m < 64; m <<= 1) s += __shfl_xor(s, m);
        if (lane == 0) out[0] = -s * (1.0f / 12000.0f);
    }
}

extern "C" void kernel_launch(void* const* d_in, const int* in_sizes, int n_in,
                              void* d_out, int out_size, void* d_ws, size_t ws_size,
                              hipStream_t stream)
{
    const float* y_true = (const float*)d_in[0];
    const float* y_pred = (const float*)d_in[1];
    float*    out     = (float*)d_out;
    float*    partial = (float*)d_ws;                    // 4000 floats
    unsigned* cnt     = (unsigned*)((char*)d_ws + 16384);

    hipMemsetAsync(cnt, 0, sizeof(unsigned), stream);
    cr_patch_kernel<<<4 * NPATCH, 64, 0, stream>>>(y_true, y_pred, partial, cnt, out);
}